// Round 19
// baseline (1062.696 us; speedup 1.0000x reference)
//
#include <hip/hip_runtime.h>

#define LN_EPS 1e-5f

// N=100000, E=300000.
// Pipeline: hist(cnt) -> scan(off) -> sortpos -> edge MLP (natural order,
// fp16 MFMA, NO atomics: stores weighted out-row to g_eo[sortpos[e]])
// -> node MLP: BMN=16; mm1 + mm2 both fp16 MFMA, single B-frag per k-step
// (empirical rule: multi-B-frag node MFMA corrupts; single-frag passed
// R15/R16/R18), XOR-swizzled LDS, LN via 4-wave psum combine.
// R19: occupancy 4->8 blocks/CU (launch_bounds) + k-loop unroll 2 to hide
// the A-fragment L2 latency that left R18 90% stalled.

typedef __attribute__((ext_vector_type(8))) _Float16 f16x8;
typedef __attribute__((ext_vector_type(4))) _Float16 f16x4;
typedef __attribute__((ext_vector_type(2))) _Float16 f16x2;
typedef __attribute__((ext_vector_type(4))) float f32x4;

#define MFMA16(a, b, c) __builtin_amdgcn_mfma_f32_16x16x32_f16((a), (b), (c), 0, 0, 0)

__device__ __forceinline__ unsigned pack2(float a, float b) {
  union { _Float16 h[2]; unsigned u; } v;
  v.h[0] = (_Float16)a; v.h[1] = (_Float16)b;
  return v.u;
}
__device__ __forceinline__ float lo16f(unsigned u) {
  union { unsigned u; f16x2 h; } v; v.u = u; return (float)v.h[0];
}
__device__ __forceinline__ float hi16f(unsigned u) {
  union { unsigned u; f16x2 h; } v; v.u = u; return (float)v.h[1];
}

// ---------------------------------------------------------------- static storage
#define NMAX 100000
#define EMAX 300000
__device__ _Float16 g_w1e[256 * 256];     // mw1^T [C][K] fp16 (edge MFMA)
__device__ _Float16 g_w2e[256 * 256];     // mw2^T
__device__ _Float16 g_w1T[512 * 448];     // nw1^T [C=512][K=448] fp16 (node mm1)
__device__ _Float16 g_w2T[384 * 512];     // nw2^T [C=384][K=512] fp16 (node mm2)
__device__ int g_cnt[NMAX];               // per-node in-degree
__device__ int g_off[NMAX];               // exclusive offsets
__device__ int g_cur[NMAX];               // scatter cursor
__device__ int g_spos[EMAX];              // edge e -> sorted position
__device__ int g_bsum[512];               // scan block partials
__device__ unsigned g_eo[EMAX * 128];     // edge outputs, sorted rows: 128 u32 pairs

// ---------------------------------------------------------------- sort pipeline
__global__ void zero_cnt(int n) {
  int i = blockIdx.x * blockDim.x + threadIdx.x;
  if (i < n) g_cnt[i] = 0;
}

__global__ void hist_kernel(const int* __restrict__ edge_index, int E) {
  int e = blockIdx.x * blockDim.x + threadIdx.x;
  if (e < E) atomicAdd(&g_cnt[edge_index[E + e]], 1);
}

__global__ void scan_blocks(int n) {
  __shared__ int buf[256];
  int idx = blockIdx.x * 256 + threadIdx.x;
  int v = (idx < n) ? g_cnt[idx] : 0;
  buf[threadIdx.x] = v; __syncthreads();
  #pragma unroll
  for (int d = 1; d < 256; d <<= 1) {
    int t = (threadIdx.x >= d) ? buf[threadIdx.x - d] : 0;
    __syncthreads();
    buf[threadIdx.x] += t;
    __syncthreads();
  }
  int incl = buf[threadIdx.x];
  if (idx < n) g_off[idx] = incl - v;
  if (threadIdx.x == 255) g_bsum[blockIdx.x] = incl;
}

__global__ void scan_single(int nb) {
  __shared__ int buf[512];
  int v = ((int)threadIdx.x < nb) ? g_bsum[threadIdx.x] : 0;
  buf[threadIdx.x] = v; __syncthreads();
  #pragma unroll
  for (int d = 1; d < 512; d <<= 1) {
    int t = (threadIdx.x >= d) ? buf[threadIdx.x - d] : 0;
    __syncthreads();
    buf[threadIdx.x] += t;
    __syncthreads();
  }
  if ((int)threadIdx.x < nb) g_bsum[threadIdx.x] = buf[threadIdx.x] - v;
}

__global__ void scan_fix(int n) {
  int idx = blockIdx.x * 256 + threadIdx.x;
  if (idx < n) {
    int v = g_off[idx] + g_bsum[blockIdx.x];
    g_off[idx] = v;
    g_cur[idx] = v;
  }
}

__global__ void scatter_kernel(const int* __restrict__ edge_index, int E) {
  int e = blockIdx.x * blockDim.x + threadIdx.x;
  if (e < E) {
    int c = edge_index[E + e];
    g_spos[e] = atomicAdd(&g_cur[c], 1);
  }
}

// ---------------------------------------------------------------- weight prep
__global__ void prep_all(const float* __restrict__ mw1, const float* __restrict__ mw2,
                         const float* __restrict__ nw1, const float* __restrict__ nw2) {
  int id = blockIdx.x * blockDim.x + threadIdx.x;
  if (id < 65536) {                              // mw1^T fp16
    int c = id >> 8, k = id & 255;
    g_w1e[id] = (_Float16)mw1[k * 256 + c];
  } else if (id < 131072) {                      // mw2^T fp16
    int j = id - 65536; int c = j >> 8, k = j & 255;
    g_w2e[j] = (_Float16)mw2[k * 256 + c];
  } else if (id < 131072 + 229376) {             // nw1^T fp16: [512][448]
    int j = id - 131072; int c = j / 448, k = j - c * 448;
    g_w1T[j] = (_Float16)nw1[k * 512 + c];
  } else if (id < 131072 + 229376 + 196608) {    // nw2^T fp16: [384][512]
    int j = id - 131072 - 229376; int c = j >> 9, k = j & 511;
    g_w2T[j] = (_Float16)nw2[k * 384 + c];
  }
}

// ---------------------------------------------------------------- edge MLP (natural order, no atomics)
constexpr int BME = 64;

__global__ __launch_bounds__(256, 2)
void edge_mfma(const float* __restrict__ x,
               const int* __restrict__ edge_index,
               const float* __restrict__ edge_attr,
               const float* __restrict__ wts,
               const float* __restrict__ mb1, const float* __restrict__ mg1,
               const float* __restrict__ mbe1,
               const float* __restrict__ mb2,
               int E)
{
  __shared__ __align__(16) unsigned char tile[BME * 512];   // 64 x 256 fp16, swizzled
  __shared__ __align__(16) float psum[BME * 4];
  __shared__ __align__(16) float psq [BME * 4];
  __shared__ int   s_row[BME];
  __shared__ int   s_pos[BME];
  __shared__ float s_wts[BME];

  const int tid = threadIdx.x;
  const int e0  = blockIdx.x * BME;

  if (tid < BME) {
    int eg = e0 + tid;
    bool v = eg < E;
    s_row[tid] = v ? edge_index[eg] : 0;
    s_pos[tid] = v ? g_spos[eg]     : 0;
    s_wts[tid] = v ? wts[eg]        : 0.f;
  }
  __syncthreads();

  #pragma unroll
  for (int it = 0; it < 16; ++it) {
    int chunk = it * 256 + tid;
    int r = chunk >> 6, ch = chunk & 63;
    int eg = e0 + r;
    float4 v = make_float4(0.f, 0.f, 0.f, 0.f);
    if (eg < E) {
      const float* src = (ch < 32) ? x + (long)s_row[r] * 128 + ch * 4
                                   : edge_attr + (long)eg * 128 + (ch - 32) * 4;
      v = *(const float4*)src;
    }
    f16x4 b;
    b[0] = (_Float16)v.x; b[1] = (_Float16)v.y;
    b[2] = (_Float16)v.z; b[3] = (_Float16)v.w;
    *(f16x4*)(tile + r * 512 + ((ch * 8) ^ ((r & 7) << 4))) = b;
  }
  __syncthreads();

  const int wv = tid >> 6, ln = tid & 63;
  const int lr = ln & 15, lh = ln >> 4;

  f32x4 acc[4][4];
  #pragma unroll
  for (int cf = 0; cf < 4; ++cf)
    #pragma unroll
    for (int nf = 0; nf < 4; ++nf)
      acc[cf][nf] = (f32x4){0.f, 0.f, 0.f, 0.f};

  {
    const _Float16* aptr = g_w1e + ((wv * 64 + lr) * 256 + lh * 8);
    for (int ks = 0; ks < 8; ++ks) {
      const int k0 = ks * 32;
      f16x8 bfr[4];
      #pragma unroll
      for (int nf = 0; nf < 4; ++nf) {
        int r = nf * 16 + lr;
        bfr[nf] = *(const f16x8*)(tile + r * 512 + ((k0 * 2 + lh * 16) ^ ((r & 7) << 4)));
      }
      #pragma unroll
      for (int cf = 0; cf < 4; ++cf) {
        f16x8 a = *(const f16x8*)(aptr + cf * (16 * 256) + k0);
        #pragma unroll
        for (int nf = 0; nf < 4; ++nf)
          acc[cf][nf] = MFMA16(a, bfr[nf], acc[cf][nf]);
      }
    }
  }

  float ps[4] = {0.f, 0.f, 0.f, 0.f}, pq[4] = {0.f, 0.f, 0.f, 0.f};
  #pragma unroll
  for (int cf = 0; cf < 4; ++cf) {
    const float4 b1 = *(const float4*)(mb1 + wv * 64 + cf * 16 + lh * 4);
    #pragma unroll
    for (int nf = 0; nf < 4; ++nf) {
      f32x4 h = acc[cf][nf];
      h[0] = fmaxf(h[0] + b1.x, 0.f);
      h[1] = fmaxf(h[1] + b1.y, 0.f);
      h[2] = fmaxf(h[2] + b1.z, 0.f);
      h[3] = fmaxf(h[3] + b1.w, 0.f);
      acc[cf][nf] = h;
      ps[nf] += h[0] + h[1] + h[2] + h[3];
      pq[nf] += h[0]*h[0] + h[1]*h[1] + h[2]*h[2] + h[3]*h[3];
    }
  }
  #pragma unroll
  for (int nf = 0; nf < 4; ++nf) {
    float s = ps[nf], q = pq[nf];
    s += __shfl_xor(s, 16); s += __shfl_xor(s, 32);
    q += __shfl_xor(q, 16); q += __shfl_xor(q, 32);
    if (lh == 0) {
      psum[(nf * 16 + lr) * 4 + wv] = s;
      psq [(nf * 16 + lr) * 4 + wv] = q;
    }
  }
  __syncthreads();

  #pragma unroll
  for (int nf = 0; nf < 4; ++nf) {
    int r = nf * 16 + lr;
    float4 sv = *(const float4*)(psum + r * 4);
    float4 qv = *(const float4*)(psq  + r * 4);
    float s = sv.x + sv.y + sv.z + sv.w;
    float q = qv.x + qv.y + qv.z + qv.w;
    float mu = s * (1.f / 256.f);
    float rs = rsqrtf(q * (1.f / 256.f) - mu * mu + LN_EPS);
    #pragma unroll
    for (int cf = 0; cf < 4; ++cf) {
      const float4 g  = *(const float4*)(mg1  + wv * 64 + cf * 16 + lh * 4);
      const float4 be = *(const float4*)(mbe1 + wv * 64 + cf * 16 + lh * 4);
      f32x4 h = acc[cf][nf];
      f16x4 hb;
      hb[0] = (_Float16)((h[0] - mu) * rs * g.x + be.x);
      hb[1] = (_Float16)((h[1] - mu) * rs * g.y + be.y);
      hb[2] = (_Float16)((h[2] - mu) * rs * g.z + be.z);
      hb[3] = (_Float16)((h[3] - mu) * rs * g.w + be.w);
      int cb = wv * 128 + cf * 32 + lh * 8;
      *(f16x4*)(tile + r * 512 + (cb ^ ((r & 7) << 4))) = hb;
    }
  }
  __syncthreads();

  f32x4 acc2[4][4];
  #pragma unroll
  for (int cf = 0; cf < 4; ++cf)
    #pragma unroll
    for (int nf = 0; nf < 4; ++nf)
      acc2[cf][nf] = (f32x4){0.f, 0.f, 0.f, 0.f};

  {
    const _Float16* aptr = g_w2e + ((wv * 64 + lr) * 256 + lh * 8);
    for (int ks = 0; ks < 8; ++ks) {
      const int k0 = ks * 32;
      f16x8 bfr[4];
      #pragma unroll
      for (int nf = 0; nf < 4; ++nf) {
        int r = nf * 16 + lr;
        bfr[nf] = *(const f16x8*)(tile + r * 512 + ((k0 * 2 + lh * 16) ^ ((r & 7) << 4)));
      }
      #pragma unroll
      for (int cf = 0; cf < 4; ++cf) {
        f16x8 a = *(const f16x8*)(aptr + cf * (16 * 256) + k0);
        #pragma unroll
        for (int nf = 0; nf < 4; ++nf)
          acc2[cf][nf] = MFMA16(a, bfr[nf], acc2[cf][nf]);
      }
    }
  }

  // epilogue: (o + b2) * wt -> fp16 stores into g_eo[sorted_pos] (NO atomics)
  #pragma unroll
  for (int nf = 0; nf < 4; ++nf) {
    int r = nf * 16 + lr;
    int eg = e0 + r;
    if (eg < E) {
      float wt = s_wts[r];
      unsigned* dst = g_eo + (long)s_pos[r] * 128;
      #pragma unroll
      for (int cf = 0; cf < 4; ++cf) {
        int c0 = wv * 64 + cf * 16 + lh * 4;
        const float4 b2 = *(const float4*)(mb2 + c0);
        f32x4 o = acc2[cf][nf];
        uint2 w;
        w.x = pack2((o[0] + b2.x) * wt, (o[1] + b2.y) * wt);
        w.y = pack2((o[2] + b2.z) * wt, (o[3] + b2.w) * wt);
        *(uint2*)(dst + (c0 >> 1)) = w;
      }
    }
  }
}

// ---------------------------------------------------------------- node MLP (MFMA mm1 + MFMA mm2, single B-frag each)
constexpr int BMN = 16;

__global__ __launch_bounds__(256, 8)
void node_mfma2(const float* __restrict__ x,
                const float* __restrict__ u,
                const int* __restrict__ node_batch,
                const float* __restrict__ nb1, const float* __restrict__ ng1,
                const float* __restrict__ nbe1,
                const float* __restrict__ nb2,
                float* __restrict__ out, int N)
{
  // in rows: 896 B stride (448 fp16); h rows: 1024 B stride (512 fp16).
  // Both XOR-swizzled: byte_in_row ^= (row&7)<<4.
  __shared__ __align__(16) unsigned char tile[BMN * 1024];  // 16 KiB, reused
  __shared__ float psum[BMN * 4];
  __shared__ float psq [BMN * 4];
  __shared__ float s_rc[BMN];
  __shared__ int   s_off[BMN];
  __shared__ int   s_cnt[BMN];
  __shared__ int   s_nb[BMN];

  const int tid = threadIdx.x;
  const int n0  = blockIdx.x * BMN;

  if (tid < BMN) {
    int ng = n0 + tid;
    bool v = ng < N;
    int cnt = v ? g_cnt[ng] : 0;
    s_cnt[tid] = cnt;
    s_off[tid] = v ? g_off[ng] : 0;
    s_rc[tid]  = 1.f / fmaxf((float)cnt, 1.f);
    s_nb[tid]  = v ? node_batch[ng] : 0;
  }
  __syncthreads();

  // stage in = concat(x, gathered received, u[nb]) packed f16 pairs, swizzled
  for (int r = 0; r < BMN; ++r) {
    int j = tid;
    if (j < 224) {
      int ng = n0 + r;
      unsigned pv = pack2(0.f, 0.f);
      if (ng < N) {
        if (j < 64) {
          float2 v = *(const float2*)(x + (long)ng * 128 + 2 * j);
          pv = pack2(v.x, v.y);
        } else if (j < 192) {
          int jj = j - 64;
          const int off = s_off[r], cnt = s_cnt[r];
          float a = 0.f, b = 0.f;
          for (int d = 0; d < cnt; ++d) {
            unsigned ev = g_eo[(long)(off + d) * 128 + jj];
            a += lo16f(ev); b += hi16f(ev);
          }
          float rc = s_rc[r];
          pv = pack2(a * rc, b * rc);
        } else {
          float2 v = *(const float2*)(u + (long)s_nb[r] * 64 + 2 * (j - 192));
          pv = pack2(v.x, v.y);
        }
      }
      *(unsigned*)(tile + r * 896 + ((4 * j) ^ ((r & 7) << 4))) = pv;
    }
  }
  __syncthreads();

  const int wv = tid >> 6, ln = tid & 63;
  const int lr = ln & 15, lh = ln >> 4;

  // ---- mm1 (MFMA): wave covers out-cols [wv*128, +128) (8 frags), rows 0..15
  f32x4 acc[8];
  #pragma unroll
  for (int cf = 0; cf < 8; ++cf) acc[cf] = (f32x4){0.f, 0.f, 0.f, 0.f};

  {
    const _Float16* ap = g_w1T + ((wv * 128 + lr) * 448 + lh * 8);
    #pragma unroll 2
    for (int ks = 0; ks < 14; ++ks) {
      const int k0 = ks * 32;
      f16x8 b = *(const f16x8*)(tile + lr * 896 + ((k0 * 2 + lh * 16) ^ ((lr & 7) << 4)));
      #pragma unroll
      for (int cf = 0; cf < 8; ++cf) {
        f16x8 a = *(const f16x8*)(ap + cf * (16 * 448) + k0);
        acc[cf] = MFMA16(a, b, acc[cf]);
      }
    }
  }

  // bias + relu + per-wave LN partials (row lr, 128 cols of this wave)
  float s = 0.f, q = 0.f;
  #pragma unroll
  for (int cf = 0; cf < 8; ++cf) {
    const float4 b1 = *(const float4*)(nb1 + wv * 128 + cf * 16 + lh * 4);
    f32x4 h = acc[cf];
    h[0] = fmaxf(h[0] + b1.x, 0.f);
    h[1] = fmaxf(h[1] + b1.y, 0.f);
    h[2] = fmaxf(h[2] + b1.z, 0.f);
    h[3] = fmaxf(h[3] + b1.w, 0.f);
    acc[cf] = h;
    s += h[0] + h[1] + h[2] + h[3];
    q += h[0]*h[0] + h[1]*h[1] + h[2]*h[2] + h[3]*h[3];
  }
  s += __shfl_xor(s, 16); s += __shfl_xor(s, 32);
  q += __shfl_xor(q, 16); q += __shfl_xor(q, 32);
  if (lh == 0) { psum[lr * 4 + wv] = s; psq[lr * 4 + wv] = q; }
  __syncthreads();   // psum ready AND all mm1 in-tile reads complete

  // LN apply + write h (packed u32, swizzled 1024 B rows)
  {
    float4 sv = *(const float4*)(psum + lr * 4);
    float4 qv = *(const float4*)(psq  + lr * 4);
    float ss = sv.x + sv.y + sv.z + sv.w;
    float qq = qv.x + qv.y + qv.z + qv.w;
    float mu = ss * (1.f / 512.f);
    float rs = rsqrtf(qq * (1.f / 512.f) - mu * mu + LN_EPS);
    #pragma unroll
    for (int cf = 0; cf < 8; ++cf) {
      const float4 g  = *(const float4*)(ng1  + wv * 128 + cf * 16 + lh * 4);
      const float4 be = *(const float4*)(nbe1 + wv * 128 + cf * 16 + lh * 4);
      f32x4 h = acc[cf];
      float h0 = (h[0] - mu) * rs * g.x + be.x;
      float h1 = (h[1] - mu) * rs * g.y + be.y;
      float h2 = (h[2] - mu) * rs * g.z + be.z;
      float h3 = (h[3] - mu) * rs * g.w + be.w;
      uint2 hw;
      hw.x = pack2(h0, h1);
      hw.y = pack2(h2, h3);
      int cb = (wv * 128 + cf * 16 + lh * 4) * 2;   // byte offset of col pair group
      *(uint2*)(tile + lr * 1024 + (cb ^ ((lr & 7) << 4))) = hw;
    }
  }
  __syncthreads();

  // ---- mm2 (MFMA): out^T = W2^T(A) x h^T(B); wave covers out-cols
  //      [wv*96, +96) (6 frags), rows 0..15 (single B-frag)
  f32x4 acc2[6];
  #pragma unroll
  for (int cf = 0; cf < 6; ++cf) acc2[cf] = (f32x4){0.f, 0.f, 0.f, 0.f};

  {
    const _Float16* ap2 = g_w2T + ((wv * 96 + lr) * 512 + lh * 8);
    #pragma unroll 2
    for (int ks = 0; ks < 16; ++ks) {
      const int k0 = ks * 32;
      f16x8 b = *(const f16x8*)(tile + lr * 1024 + ((k0 * 2 + lh * 16) ^ ((lr & 7) << 4)));
      #pragma unroll
      for (int cf = 0; cf < 6; ++cf) {
        f16x8 a = *(const f16x8*)(ap2 + cf * (16 * 512) + k0);
        acc2[cf] = MFMA16(a, b, acc2[cf]);
      }
    }
  }

  // epilogue: row lr, cols wv*96 + cf*16 + lh*4 (float4 stores + bias)
  {
    long ng = n0 + lr;
    if (ng < N) {
      #pragma unroll
      for (int cf = 0; cf < 6; ++cf) {
        int c0 = wv * 96 + cf * 16 + lh * 4;
        const float4 b2 = *(const float4*)(nb2 + c0);
        f32x4 o = acc2[cf];
        float4 res = make_float4(o[0] + b2.x, o[1] + b2.y, o[2] + b2.z, o[3] + b2.w);
        *(float4*)(out + ng * 384 + c0) = res;
      }
    }
  }
}

// ---------------------------------------------------------------- launch
extern "C" void kernel_launch(void* const* d_in, const int* in_sizes, int n_in,
                              void* d_out, int out_size, void* d_ws, size_t ws_size,
                              hipStream_t stream)
{
  const float* x          = (const float*)d_in[0];
  const int*   edge_index = (const int*)  d_in[1];
  const float* edge_attr  = (const float*)d_in[2];
  const float* u          = (const float*)d_in[3];
  const int*   node_batch = (const int*)  d_in[4];
  // d_in[5] edge_batch unused
  const float* wts        = (const float*)d_in[6];
  const float* mw1  = (const float*)d_in[7];
  const float* mb1  = (const float*)d_in[8];
  const float* mg1  = (const float*)d_in[9];
  const float* mbe1 = (const float*)d_in[10];
  const float* mw2  = (const float*)d_in[11];
  const float* mb2  = (const float*)d_in[12];
  const float* nw1  = (const float*)d_in[13];
  const float* nb1  = (const float*)d_in[14];
  const float* ng1  = (const float*)d_in[15];
  const float* nbe1 = (const float*)d_in[16];
  const float* nw2  = (const float*)d_in[17];
  const float* nb2  = (const float*)d_in[18];
  float* out = (float*)d_out;

  const int N = in_sizes[0] / 128;   // 100000
  const int E = in_sizes[2] / 128;   // 300000
  const int nb = (N + 255) / 256;    // scan blocks (391)

  zero_cnt<<<nb, 256, 0, stream>>>(N);
  prep_all<<<(557056 + 255) / 256, 256, 0, stream>>>(mw1, mw2, nw1, nw2);

  // counting sort metadata: cnt, off, sortpos
  hist_kernel<<<(E + 255) / 256, 256, 0, stream>>>(edge_index, E);
  scan_blocks<<<nb, 256, 0, stream>>>(N);
  scan_single<<<1, 512, 0, stream>>>(nb);
  scan_fix<<<nb, 256, 0, stream>>>(N);
  scatter_kernel<<<(E + 255) / 256, 256, 0, stream>>>(edge_index, E);

  edge_mfma<<<(E + BME - 1) / BME, 256, 0, stream>>>(
      x, edge_index, edge_attr, wts, mb1, mg1, mbe1, mb2, E);

  node_mfma2<<<(N + BMN - 1) / BMN, 256, 0, stream>>>(
      x, u, node_batch, nb1, ng1, nbe1, nb2, out, N);
}

// Round 20
// 715.408 us; speedup vs baseline: 1.4854x; 1.4854x over previous
//
#include <hip/hip_runtime.h>

#define LN_EPS 1e-5f

// N=100000, E=300000.
// Pipeline: hist(cnt) -> scan(off) -> sortpos -> edge MLP (natural order,
// fp16 MFMA, NO atomics: stores weighted out-row to g_eo[sortpos[e]])
// -> node MLP: BMN=16; mm1 + mm2 both fp16 MFMA, single B-frag per k-step
// (empirical rule: multi-B-frag node MFMA corrupts; single-frag passed
// R15/R16/R18/R19), XOR-swizzled LDS, LN via 4-wave psum combine.
// R20: node weights stored FRAGMENT-MAJOR (g_w1f/g_w2f): each MFMA A-load
// is one coalesced 1KB burst (was 16 scattered cache lines) -> fixes the
// TA-transaction bottleneck that made R18/R19 occupancy-independent.

typedef __attribute__((ext_vector_type(8))) _Float16 f16x8;
typedef __attribute__((ext_vector_type(4))) _Float16 f16x4;
typedef __attribute__((ext_vector_type(2))) _Float16 f16x2;
typedef __attribute__((ext_vector_type(4))) float f32x4;

#define MFMA16(a, b, c) __builtin_amdgcn_mfma_f32_16x16x32_f16((a), (b), (c), 0, 0, 0)

__device__ __forceinline__ unsigned pack2(float a, float b) {
  union { _Float16 h[2]; unsigned u; } v;
  v.h[0] = (_Float16)a; v.h[1] = (_Float16)b;
  return v.u;
}
__device__ __forceinline__ float lo16f(unsigned u) {
  union { unsigned u; f16x2 h; } v; v.u = u; return (float)v.h[0];
}
__device__ __forceinline__ float hi16f(unsigned u) {
  union { unsigned u; f16x2 h; } v; v.u = u; return (float)v.h[1];
}

// ---------------------------------------------------------------- static storage
#define NMAX 100000
#define EMAX 300000
__device__ _Float16 g_w1e[256 * 256];     // mw1^T [C][K] fp16 (edge MFMA)
__device__ _Float16 g_w2e[256 * 256];     // mw2^T
__device__ _Float16 g_w1f[32 * 14 * 512]; // nw1 fragment-major: [cb16*14+ks][ln*8+e]
__device__ _Float16 g_w2f[24 * 16 * 512]; // nw2 fragment-major: [cb16*16+ks][ln*8+e]
__device__ int g_cnt[NMAX];               // per-node in-degree
__device__ int g_off[NMAX];               // exclusive offsets
__device__ int g_cur[NMAX];               // scatter cursor
__device__ int g_spos[EMAX];              // edge e -> sorted position
__device__ int g_bsum[512];               // scan block partials
__device__ unsigned g_eo[EMAX * 128];     // edge outputs, sorted rows: 128 u32 pairs

// ---------------------------------------------------------------- sort pipeline
__global__ void zero_cnt(int n) {
  int i = blockIdx.x * blockDim.x + threadIdx.x;
  if (i < n) g_cnt[i] = 0;
}

__global__ void hist_kernel(const int* __restrict__ edge_index, int E) {
  int e = blockIdx.x * blockDim.x + threadIdx.x;
  if (e < E) atomicAdd(&g_cnt[edge_index[E + e]], 1);
}

__global__ void scan_blocks(int n) {
  __shared__ int buf[256];
  int idx = blockIdx.x * 256 + threadIdx.x;
  int v = (idx < n) ? g_cnt[idx] : 0;
  buf[threadIdx.x] = v; __syncthreads();
  #pragma unroll
  for (int d = 1; d < 256; d <<= 1) {
    int t = (threadIdx.x >= d) ? buf[threadIdx.x - d] : 0;
    __syncthreads();
    buf[threadIdx.x] += t;
    __syncthreads();
  }
  int incl = buf[threadIdx.x];
  if (idx < n) g_off[idx] = incl - v;
  if (threadIdx.x == 255) g_bsum[blockIdx.x] = incl;
}

__global__ void scan_single(int nb) {
  __shared__ int buf[512];
  int v = ((int)threadIdx.x < nb) ? g_bsum[threadIdx.x] : 0;
  buf[threadIdx.x] = v; __syncthreads();
  #pragma unroll
  for (int d = 1; d < 512; d <<= 1) {
    int t = (threadIdx.x >= d) ? buf[threadIdx.x - d] : 0;
    __syncthreads();
    buf[threadIdx.x] += t;
    __syncthreads();
  }
  if ((int)threadIdx.x < nb) g_bsum[threadIdx.x] = buf[threadIdx.x] - v;
}

__global__ void scan_fix(int n) {
  int idx = blockIdx.x * 256 + threadIdx.x;
  if (idx < n) {
    int v = g_off[idx] + g_bsum[blockIdx.x];
    g_off[idx] = v;
    g_cur[idx] = v;
  }
}

__global__ void scatter_kernel(const int* __restrict__ edge_index, int E) {
  int e = blockIdx.x * blockDim.x + threadIdx.x;
  if (e < E) {
    int c = edge_index[E + e];
    g_spos[e] = atomicAdd(&g_cur[c], 1);
  }
}

// ---------------------------------------------------------------- weight prep
__global__ void prep_all(const float* __restrict__ mw1, const float* __restrict__ mw2,
                         const float* __restrict__ nw1, const float* __restrict__ nw2) {
  int id = blockIdx.x * blockDim.x + threadIdx.x;
  if (id < 65536) {                              // mw1^T fp16
    int c = id >> 8, k = id & 255;
    g_w1e[id] = (_Float16)mw1[k * 256 + c];
  } else if (id < 131072) {                      // mw2^T fp16
    int j = id - 65536; int c = j >> 8, k = j & 255;
    g_w2e[j] = (_Float16)mw2[k * 256 + c];
  } else if (id < 131072 + 229376) {             // nw1 fragment-major
    int j = id - 131072;
    int frag = j >> 9, r = j & 511;
    int ln = r >> 3, e = r & 7;
    int cb16 = frag / 14, ks = frag - cb16 * 14;
    int lr = ln & 15, lh = ln >> 4;
    int col = cb16 * 16 + lr;
    int k = ks * 32 + lh * 8 + e;
    g_w1f[j] = (_Float16)nw1[k * 512 + col];
  } else if (id < 131072 + 229376 + 196608) {    // nw2 fragment-major
    int j = id - 131072 - 229376;
    int frag = j >> 9, r = j & 511;
    int ln = r >> 3, e = r & 7;
    int cb16 = frag >> 4, ks = frag & 15;
    int lr = ln & 15, lh = ln >> 4;
    int col = cb16 * 16 + lr;
    int k = ks * 32 + lh * 8 + e;
    g_w2f[j] = (_Float16)nw2[k * 384 + col];
  }
}

// ---------------------------------------------------------------- edge MLP (natural order, no atomics)
constexpr int BME = 64;

__global__ __launch_bounds__(256, 2)
void edge_mfma(const float* __restrict__ x,
               const int* __restrict__ edge_index,
               const float* __restrict__ edge_attr,
               const float* __restrict__ wts,
               const float* __restrict__ mb1, const float* __restrict__ mg1,
               const float* __restrict__ mbe1,
               const float* __restrict__ mb2,
               int E)
{
  __shared__ __align__(16) unsigned char tile[BME * 512];   // 64 x 256 fp16, swizzled
  __shared__ __align__(16) float psum[BME * 4];
  __shared__ __align__(16) float psq [BME * 4];
  __shared__ int   s_row[BME];
  __shared__ int   s_pos[BME];
  __shared__ float s_wts[BME];

  const int tid = threadIdx.x;
  const int e0  = blockIdx.x * BME;

  if (tid < BME) {
    int eg = e0 + tid;
    bool v = eg < E;
    s_row[tid] = v ? edge_index[eg] : 0;
    s_pos[tid] = v ? g_spos[eg]     : 0;
    s_wts[tid] = v ? wts[eg]        : 0.f;
  }
  __syncthreads();

  #pragma unroll
  for (int it = 0; it < 16; ++it) {
    int chunk = it * 256 + tid;
    int r = chunk >> 6, ch = chunk & 63;
    int eg = e0 + r;
    float4 v = make_float4(0.f, 0.f, 0.f, 0.f);
    if (eg < E) {
      const float* src = (ch < 32) ? x + (long)s_row[r] * 128 + ch * 4
                                   : edge_attr + (long)eg * 128 + (ch - 32) * 4;
      v = *(const float4*)src;
    }
    f16x4 b;
    b[0] = (_Float16)v.x; b[1] = (_Float16)v.y;
    b[2] = (_Float16)v.z; b[3] = (_Float16)v.w;
    *(f16x4*)(tile + r * 512 + ((ch * 8) ^ ((r & 7) << 4))) = b;
  }
  __syncthreads();

  const int wv = tid >> 6, ln = tid & 63;
  const int lr = ln & 15, lh = ln >> 4;

  f32x4 acc[4][4];
  #pragma unroll
  for (int cf = 0; cf < 4; ++cf)
    #pragma unroll
    for (int nf = 0; nf < 4; ++nf)
      acc[cf][nf] = (f32x4){0.f, 0.f, 0.f, 0.f};

  {
    const _Float16* aptr = g_w1e + ((wv * 64 + lr) * 256 + lh * 8);
    for (int ks = 0; ks < 8; ++ks) {
      const int k0 = ks * 32;
      f16x8 bfr[4];
      #pragma unroll
      for (int nf = 0; nf < 4; ++nf) {
        int r = nf * 16 + lr;
        bfr[nf] = *(const f16x8*)(tile + r * 512 + ((k0 * 2 + lh * 16) ^ ((r & 7) << 4)));
      }
      #pragma unroll
      for (int cf = 0; cf < 4; ++cf) {
        f16x8 a = *(const f16x8*)(aptr + cf * (16 * 256) + k0);
        #pragma unroll
        for (int nf = 0; nf < 4; ++nf)
          acc[cf][nf] = MFMA16(a, bfr[nf], acc[cf][nf]);
      }
    }
  }

  float ps[4] = {0.f, 0.f, 0.f, 0.f}, pq[4] = {0.f, 0.f, 0.f, 0.f};
  #pragma unroll
  for (int cf = 0; cf < 4; ++cf) {
    const float4 b1 = *(const float4*)(mb1 + wv * 64 + cf * 16 + lh * 4);
    #pragma unroll
    for (int nf = 0; nf < 4; ++nf) {
      f32x4 h = acc[cf][nf];
      h[0] = fmaxf(h[0] + b1.x, 0.f);
      h[1] = fmaxf(h[1] + b1.y, 0.f);
      h[2] = fmaxf(h[2] + b1.z, 0.f);
      h[3] = fmaxf(h[3] + b1.w, 0.f);
      acc[cf][nf] = h;
      ps[nf] += h[0] + h[1] + h[2] + h[3];
      pq[nf] += h[0]*h[0] + h[1]*h[1] + h[2]*h[2] + h[3]*h[3];
    }
  }
  #pragma unroll
  for (int nf = 0; nf < 4; ++nf) {
    float s = ps[nf], q = pq[nf];
    s += __shfl_xor(s, 16); s += __shfl_xor(s, 32);
    q += __shfl_xor(q, 16); q += __shfl_xor(q, 32);
    if (lh == 0) {
      psum[(nf * 16 + lr) * 4 + wv] = s;
      psq [(nf * 16 + lr) * 4 + wv] = q;
    }
  }
  __syncthreads();

  #pragma unroll
  for (int nf = 0; nf < 4; ++nf) {
    int r = nf * 16 + lr;
    float4 sv = *(const float4*)(psum + r * 4);
    float4 qv = *(const float4*)(psq  + r * 4);
    float s = sv.x + sv.y + sv.z + sv.w;
    float q = qv.x + qv.y + qv.z + qv.w;
    float mu = s * (1.f / 256.f);
    float rs = rsqrtf(q * (1.f / 256.f) - mu * mu + LN_EPS);
    #pragma unroll
    for (int cf = 0; cf < 4; ++cf) {
      const float4 g  = *(const float4*)(mg1  + wv * 64 + cf * 16 + lh * 4);
      const float4 be = *(const float4*)(mbe1 + wv * 64 + cf * 16 + lh * 4);
      f32x4 h = acc[cf][nf];
      f16x4 hb;
      hb[0] = (_Float16)((h[0] - mu) * rs * g.x + be.x);
      hb[1] = (_Float16)((h[1] - mu) * rs * g.y + be.y);
      hb[2] = (_Float16)((h[2] - mu) * rs * g.z + be.z);
      hb[3] = (_Float16)((h[3] - mu) * rs * g.w + be.w);
      int cb = wv * 128 + cf * 32 + lh * 8;
      *(f16x4*)(tile + r * 512 + (cb ^ ((r & 7) << 4))) = hb;
    }
  }
  __syncthreads();

  f32x4 acc2[4][4];
  #pragma unroll
  for (int cf = 0; cf < 4; ++cf)
    #pragma unroll
    for (int nf = 0; nf < 4; ++nf)
      acc2[cf][nf] = (f32x4){0.f, 0.f, 0.f, 0.f};

  {
    const _Float16* aptr = g_w2e + ((wv * 64 + lr) * 256 + lh * 8);
    for (int ks = 0; ks < 8; ++ks) {
      const int k0 = ks * 32;
      f16x8 bfr[4];
      #pragma unroll
      for (int nf = 0; nf < 4; ++nf) {
        int r = nf * 16 + lr;
        bfr[nf] = *(const f16x8*)(tile + r * 512 + ((k0 * 2 + lh * 16) ^ ((r & 7) << 4)));
      }
      #pragma unroll
      for (int cf = 0; cf < 4; ++cf) {
        f16x8 a = *(const f16x8*)(aptr + cf * (16 * 256) + k0);
        #pragma unroll
        for (int nf = 0; nf < 4; ++nf)
          acc2[cf][nf] = MFMA16(a, bfr[nf], acc2[cf][nf]);
      }
    }
  }

  // epilogue: (o + b2) * wt -> fp16 stores into g_eo[sorted_pos] (NO atomics)
  #pragma unroll
  for (int nf = 0; nf < 4; ++nf) {
    int r = nf * 16 + lr;
    int eg = e0 + r;
    if (eg < E) {
      float wt = s_wts[r];
      unsigned* dst = g_eo + (long)s_pos[r] * 128;
      #pragma unroll
      for (int cf = 0; cf < 4; ++cf) {
        int c0 = wv * 64 + cf * 16 + lh * 4;
        const float4 b2 = *(const float4*)(mb2 + c0);
        f32x4 o = acc2[cf][nf];
        uint2 w;
        w.x = pack2((o[0] + b2.x) * wt, (o[1] + b2.y) * wt);
        w.y = pack2((o[2] + b2.z) * wt, (o[3] + b2.w) * wt);
        *(uint2*)(dst + (c0 >> 1)) = w;
      }
    }
  }
}

// ---------------------------------------------------------------- node MLP (MFMA mm1 + MFMA mm2, single B-frag each)
constexpr int BMN = 16;

__global__ __launch_bounds__(256, 8)
void node_mfma2(const float* __restrict__ x,
                const float* __restrict__ u,
                const int* __restrict__ node_batch,
                const float* __restrict__ nb1, const float* __restrict__ ng1,
                const float* __restrict__ nbe1,
                const float* __restrict__ nb2,
                float* __restrict__ out, int N)
{
  // in rows: 896 B stride (448 fp16); h rows: 1024 B stride (512 fp16).
  // Both XOR-swizzled: byte_in_row ^= (row&7)<<4.
  __shared__ __align__(16) unsigned char tile[BMN * 1024];  // 16 KiB, reused
  __shared__ float psum[BMN * 4];
  __shared__ float psq [BMN * 4];
  __shared__ float s_rc[BMN];
  __shared__ int   s_off[BMN];
  __shared__ int   s_cnt[BMN];
  __shared__ int   s_nb[BMN];

  const int tid = threadIdx.x;
  const int n0  = blockIdx.x * BMN;

  if (tid < BMN) {
    int ng = n0 + tid;
    bool v = ng < N;
    int cnt = v ? g_cnt[ng] : 0;
    s_cnt[tid] = cnt;
    s_off[tid] = v ? g_off[ng] : 0;
    s_rc[tid]  = 1.f / fmaxf((float)cnt, 1.f);
    s_nb[tid]  = v ? node_batch[ng] : 0;
  }
  __syncthreads();

  // stage in = concat(x, gathered received, u[nb]) packed f16 pairs, swizzled
  for (int r = 0; r < BMN; ++r) {
    int j = tid;
    if (j < 224) {
      int ng = n0 + r;
      unsigned pv = pack2(0.f, 0.f);
      if (ng < N) {
        if (j < 64) {
          float2 v = *(const float2*)(x + (long)ng * 128 + 2 * j);
          pv = pack2(v.x, v.y);
        } else if (j < 192) {
          int jj = j - 64;
          const int off = s_off[r], cnt = s_cnt[r];
          float a = 0.f, b = 0.f;
          for (int d = 0; d < cnt; ++d) {
            unsigned ev = g_eo[(long)(off + d) * 128 + jj];
            a += lo16f(ev); b += hi16f(ev);
          }
          float rc = s_rc[r];
          pv = pack2(a * rc, b * rc);
        } else {
          float2 v = *(const float2*)(u + (long)s_nb[r] * 64 + 2 * (j - 192));
          pv = pack2(v.x, v.y);
        }
      }
      *(unsigned*)(tile + r * 896 + ((4 * j) ^ ((r & 7) << 4))) = pv;
    }
  }
  __syncthreads();

  const int wv = tid >> 6, ln = tid & 63;
  const int lr = ln & 15, lh = ln >> 4;

  // ---- mm1 (MFMA): wave covers out-cols [wv*128, +128) (8 frags), rows 0..15
  f32x4 acc[8];
  #pragma unroll
  for (int cf = 0; cf < 8; ++cf) acc[cf] = (f32x4){0.f, 0.f, 0.f, 0.f};

  {
    // fragment-major A: g_w1f[((wv*8+cf)*14 + ks)*512 + ln*8] -- coalesced 1KB
    const _Float16* ap = g_w1f + (long)(wv * 8) * 14 * 512 + ln * 8;
    #pragma unroll 2
    for (int ks = 0; ks < 14; ++ks) {
      const int k0 = ks * 32;
      f16x8 b = *(const f16x8*)(tile + lr * 896 + ((k0 * 2 + lh * 16) ^ ((lr & 7) << 4)));
      #pragma unroll
      for (int cf = 0; cf < 8; ++cf) {
        f16x8 a = *(const f16x8*)(ap + (cf * 14 + ks) * 512);
        acc[cf] = MFMA16(a, b, acc[cf]);
      }
    }
  }

  // bias + relu + per-wave LN partials (row lr, 128 cols of this wave)
  float s = 0.f, q = 0.f;
  #pragma unroll
  for (int cf = 0; cf < 8; ++cf) {
    const float4 b1 = *(const float4*)(nb1 + wv * 128 + cf * 16 + lh * 4);
    f32x4 h = acc[cf];
    h[0] = fmaxf(h[0] + b1.x, 0.f);
    h[1] = fmaxf(h[1] + b1.y, 0.f);
    h[2] = fmaxf(h[2] + b1.z, 0.f);
    h[3] = fmaxf(h[3] + b1.w, 0.f);
    acc[cf] = h;
    s += h[0] + h[1] + h[2] + h[3];
    q += h[0]*h[0] + h[1]*h[1] + h[2]*h[2] + h[3]*h[3];
  }
  s += __shfl_xor(s, 16); s += __shfl_xor(s, 32);
  q += __shfl_xor(q, 16); q += __shfl_xor(q, 32);
  if (lh == 0) { psum[lr * 4 + wv] = s; psq[lr * 4 + wv] = q; }
  __syncthreads();   // psum ready AND all mm1 in-tile reads complete

  // LN apply + write h (packed u32, swizzled 1024 B rows)
  {
    float4 sv = *(const float4*)(psum + lr * 4);
    float4 qv = *(const float4*)(psq  + lr * 4);
    float ss = sv.x + sv.y + sv.z + sv.w;
    float qq = qv.x + qv.y + qv.z + qv.w;
    float mu = ss * (1.f / 512.f);
    float rs = rsqrtf(qq * (1.f / 512.f) - mu * mu + LN_EPS);
    #pragma unroll
    for (int cf = 0; cf < 8; ++cf) {
      const float4 g  = *(const float4*)(ng1  + wv * 128 + cf * 16 + lh * 4);
      const float4 be = *(const float4*)(nbe1 + wv * 128 + cf * 16 + lh * 4);
      f32x4 h = acc[cf];
      float h0 = (h[0] - mu) * rs * g.x + be.x;
      float h1 = (h[1] - mu) * rs * g.y + be.y;
      float h2 = (h[2] - mu) * rs * g.z + be.z;
      float h3 = (h[3] - mu) * rs * g.w + be.w;
      uint2 hw;
      hw.x = pack2(h0, h1);
      hw.y = pack2(h2, h3);
      int cb = (wv * 128 + cf * 16 + lh * 4) * 2;   // byte offset of col pair group
      *(uint2*)(tile + lr * 1024 + (cb ^ ((lr & 7) << 4))) = hw;
    }
  }
  __syncthreads();

  // ---- mm2 (MFMA): out^T = W2(A) x h^T(B); wave covers out-cols
  //      [wv*96, +96) (6 frags), rows 0..15 (single B-frag)
  f32x4 acc2[6];
  #pragma unroll
  for (int cf = 0; cf < 6; ++cf) acc2[cf] = (f32x4){0.f, 0.f, 0.f, 0.f};

  {
    // fragment-major A: g_w2f[((wv*6+cf)*16 + ks)*512 + ln*8] -- coalesced 1KB
    const _Float16* ap2 = g_w2f + (long)(wv * 6) * 16 * 512 + ln * 8;
    #pragma unroll 2
    for (int ks = 0; ks < 16; ++ks) {
      const int k0 = ks * 32;
      f16x8 b = *(const f16x8*)(tile + lr * 1024 + ((k0 * 2 + lh * 16) ^ ((lr & 7) << 4)));
      #pragma unroll
      for (int cf = 0; cf < 6; ++cf) {
        f16x8 a = *(const f16x8*)(ap2 + (cf * 16 + ks) * 512);
        acc2[cf] = MFMA16(a, b, acc2[cf]);
      }
    }
  }

  // epilogue: row lr, cols wv*96 + cf*16 + lh*4 (float4 stores + bias)
  {
    long ng = n0 + lr;
    if (ng < N) {
      #pragma unroll
      for (int cf = 0; cf < 6; ++cf) {
        int c0 = wv * 96 + cf * 16 + lh * 4;
        const float4 b2 = *(const float4*)(nb2 + c0);
        f32x4 o = acc2[cf];
        float4 res = make_float4(o[0] + b2.x, o[1] + b2.y, o[2] + b2.z, o[3] + b2.w);
        *(float4*)(out + ng * 384 + c0) = res;
      }
    }
  }
}

// ---------------------------------------------------------------- launch
extern "C" void kernel_launch(void* const* d_in, const int* in_sizes, int n_in,
                              void* d_out, int out_size, void* d_ws, size_t ws_size,
                              hipStream_t stream)
{
  const float* x          = (const float*)d_in[0];
  const int*   edge_index = (const int*)  d_in[1];
  const float* edge_attr  = (const float*)d_in[2];
  const float* u          = (const float*)d_in[3];
  const int*   node_batch = (const int*)  d_in[4];
  // d_in[5] edge_batch unused
  const float* wts        = (const float*)d_in[6];
  const float* mw1  = (const float*)d_in[7];
  const float* mb1  = (const float*)d_in[8];
  const float* mg1  = (const float*)d_in[9];
  const float* mbe1 = (const float*)d_in[10];
  const float* mw2  = (const float*)d_in[11];
  const float* mb2  = (const float*)d_in[12];
  const float* nw1  = (const float*)d_in[13];
  const float* nb1  = (const float*)d_in[14];
  const float* ng1  = (const float*)d_in[15];
  const float* nbe1 = (const float*)d_in[16];
  const float* nw2  = (const float*)d_in[17];
  const float* nb2  = (const float*)d_in[18];
  float* out = (float*)d_out;

  const int N = in_sizes[0] / 128;   // 100000
  const int E = in_sizes[2] / 128;   // 300000
  const int nb = (N + 255) / 256;    // scan blocks (391)

  zero_cnt<<<nb, 256, 0, stream>>>(N);
  prep_all<<<(557056 + 255) / 256, 256, 0, stream>>>(mw1, mw2, nw1, nw2);

  // counting sort metadata: cnt, off, sortpos
  hist_kernel<<<(E + 255) / 256, 256, 0, stream>>>(edge_index, E);
  scan_blocks<<<nb, 256, 0, stream>>>(N);
  scan_single<<<1, 512, 0, stream>>>(nb);
  scan_fix<<<nb, 256, 0, stream>>>(N);
  scatter_kernel<<<(E + 255) / 256, 256, 0, stream>>>(edge_index, E);

  edge_mfma<<<(E + BME - 1) / BME, 256, 0, stream>>>(
      x, edge_index, edge_attr, wts, mb1, mg1, mbe1, mb2, E);

  node_mfma2<<<(N + BMN - 1) / BMN, 256, 0, stream>>>(
      x, u, node_batch, nb1, ng1, nbe1, nb2, out, N);
}